// Round 1
// baseline (201.187 us; speedup 1.0000x reference)
//
#include <hip/hip_runtime.h>

typedef unsigned short u16;
typedef __bf16 bf16;
typedef bf16 bf16x8 __attribute__((ext_vector_type(8)));
typedef float f32x4 __attribute__((ext_vector_type(4)));

#define S 2048
#define D 64
#define BATCH 4
#define SCL 0.022097086912079612f  /* 1/sqrt(2048) */

__device__ __forceinline__ u16 f2bf(float f) {
  union { float f; unsigned u; } v; v.f = f;
  return (u16)((v.u + 0x7FFFu + ((v.u >> 16) & 1u)) >> 16);
}

// ---- 1. W_Q, W_V -> bf16 -------------------------------------------------
__global__ void k_cvtw(const float* __restrict__ wq, const float* __restrict__ wv,
                       u16* __restrict__ wqb, u16* __restrict__ wvb) {
  const size_t N = (size_t)S * S;
  size_t idx = ((size_t)blockIdx.x * 256 + threadIdx.x) * 8;
  const float* src; u16* dst;
  if (idx < N) { src = wq + idx; dst = wqb + idx; }
  else         { src = wv + (idx - N); dst = wvb + (idx - N); }
  float4 a = *(const float4*)src;
  float4 b = *(const float4*)(src + 4);
  union { u16 s[8]; uint4 v; } u;
  u.s[0]=f2bf(a.x); u.s[1]=f2bf(a.y); u.s[2]=f2bf(a.z); u.s[3]=f2bf(a.w);
  u.s[4]=f2bf(b.x); u.s[5]=f2bf(b.y); u.s[6]=f2bf(b.z); u.s[7]=f2bf(b.w);
  *(uint4*)dst = u.v;
}

// ---- 2. chunk sums + x -> bf16 (row-major and transposed) ---------------
__global__ void k_scan_a(const float* __restrict__ x, u16* __restrict__ xb,
                         u16* __restrict__ xTb, float* __restrict__ csum) {
  int chunk = blockIdx.x, b = blockIdx.y, d = threadIdx.x;
  const float* xp = x + ((size_t)b * S + (size_t)chunk * 64) * D + d;
  float sum = 0.f;
  for (int s = 0; s < 64; ++s) {
    float v = xp[(size_t)s * D];
    sum += v;
    int sg = chunk * 64 + s;
    u16 h = f2bf(v);
    xb[((size_t)b * S + sg) * D + d] = h;
    xTb[((size_t)b * D + d) * S + sg] = h;
  }
  csum[((size_t)b * 32 + chunk) * 64 + d] = sum;
}

// ---- 3. finish scan -> GT (running mean, transposed, bf16) --------------
__global__ void k_scan_b(const float* __restrict__ x, const float* __restrict__ csum,
                         u16* __restrict__ GTb) {
  int chunk = blockIdx.x, b = blockIdx.y, d = threadIdx.x;
  float run = 0.f;
  for (int c = 0; c < chunk; ++c) run += csum[((size_t)b * 32 + c) * 64 + d];
  const float* xp = x + ((size_t)b * S + (size_t)chunk * 64) * D + d;
  for (int s = 0; s < 64; ++s) {
    run += xp[(size_t)s * D];
    int sg = chunk * 64 + s;
    GTb[((size_t)b * D + d) * S + sg] = f2bf(run / (float)(sg + 1));
  }
}

// ---- 4. GEMM1: Q = W_Q @ G, V = W_V @ x  (per batch) --------------------
// mat==0 -> Q (row-major out), mat==1 -> V (transposed out VT[d][s])
__global__ __launch_bounds__(256) void k_gemm1(
    const u16* __restrict__ wqb, const u16* __restrict__ wvb,
    const u16* __restrict__ GTb, const u16* __restrict__ xTb,
    u16* __restrict__ Qb, u16* __restrict__ VTb) {
  int mt = blockIdx.x, mat = blockIdx.y, b = blockIdx.z;
  int w = threadIdx.x >> 6, l = threadIdx.x & 63;
  int lr = l & 15, lg = l >> 4;
  int row = mt * 64 + w * 16 + lr;
  const u16* W = mat ? wvb : wqb;
  const u16* Bsrc = (mat ? xTb : GTb) + (size_t)b * D * S;
  f32x4 acc[4] = {};
  const u16* wrow = W + (size_t)row * S + lg * 8;
  const u16* brow0 = Bsrc + (size_t)(0 * 16 + lr) * S + lg * 8;
  const u16* brow1 = Bsrc + (size_t)(1 * 16 + lr) * S + lg * 8;
  const u16* brow2 = Bsrc + (size_t)(2 * 16 + lr) * S + lg * 8;
  const u16* brow3 = Bsrc + (size_t)(3 * 16 + lr) * S + lg * 8;
  for (int k0 = 0; k0 < S; k0 += 32) {
    bf16x8 a = *(const bf16x8*)(wrow + k0);
    bf16x8 b0 = *(const bf16x8*)(brow0 + k0);
    bf16x8 b1 = *(const bf16x8*)(brow1 + k0);
    bf16x8 b2 = *(const bf16x8*)(brow2 + k0);
    bf16x8 b3 = *(const bf16x8*)(brow3 + k0);
    acc[0] = __builtin_amdgcn_mfma_f32_16x16x32_bf16(a, b0, acc[0], 0, 0, 0);
    acc[1] = __builtin_amdgcn_mfma_f32_16x16x32_bf16(a, b1, acc[1], 0, 0, 0);
    acc[2] = __builtin_amdgcn_mfma_f32_16x16x32_bf16(a, b2, acc[2], 0, 0, 0);
    acc[3] = __builtin_amdgcn_mfma_f32_16x16x32_bf16(a, b3, acc[3], 0, 0, 0);
  }
#pragma unroll
  for (int dt = 0; dt < 4; ++dt)
#pragma unroll
    for (int r = 0; r < 4; ++r) {
      int m = mt * 64 + w * 16 + lg * 4 + r;
      int n = dt * 16 + lr;
      u16 hv = f2bf(acc[dt][r]);
      if (mat) VTb[((size_t)b * D + n) * S + m] = hv;
      else     Qb[((size_t)b * S + m) * D + n] = hv;
    }
}

// ---- 5. column stats: m_j = max_i a_ij, Z_j = sum_i exp(a_ij - m_j) -----
// scores^T via mfma(A=x_j, B=Q_i): C[row=j-local][col=i-local]
__global__ __launch_bounds__(256) void k_stats(
    const u16* __restrict__ xb, const u16* __restrict__ Qb,
    float* __restrict__ mbuf, float* __restrict__ rzbuf) {
  int jt = blockIdx.x, b = blockIdx.y;
  int w = threadIdx.x >> 6, l = threadIdx.x & 63;
  int lr = l & 15, lg = l >> 4;
  int j0 = jt * 64 + w * 16;
  const u16* xbase = xb + (size_t)b * S * D;
  const u16* qbase = Qb + (size_t)b * S * D;
  bf16x8 xa0 = *(const bf16x8*)(xbase + (size_t)(j0 + lr) * D + lg * 8);
  bf16x8 xa1 = *(const bf16x8*)(xbase + (size_t)(j0 + lr) * D + 32 + lg * 8);
  float m[4] = {-1e30f, -1e30f, -1e30f, -1e30f};
  float z[4] = {0.f, 0.f, 0.f, 0.f};
  for (int i16 = jt * 64; i16 < S; i16 += 16) {
    bf16x8 q0 = *(const bf16x8*)(qbase + (size_t)(i16 + lr) * D + lg * 8);
    bf16x8 q1 = *(const bf16x8*)(qbase + (size_t)(i16 + lr) * D + 32 + lg * 8);
    f32x4 c = {};
    c = __builtin_amdgcn_mfma_f32_16x16x32_bf16(xa0, q0, c, 0, 0, 0);
    c = __builtin_amdgcn_mfma_f32_16x16x32_bf16(xa1, q1, c, 0, 0, 0);
    int i = i16 + lr;
#pragma unroll
    for (int r = 0; r < 4; ++r) {
      int j = j0 + lg * 4 + r;
      float sc = c[r];
      float a = (i >= j && sc > 1.0f) ? sc * SCL : -1e30f;
      float mn = fmaxf(m[r], a);
      z[r] = z[r] * __expf(m[r] - mn) + __expf(a - mn);
      m[r] = mn;
    }
  }
#pragma unroll
  for (int r = 0; r < 4; ++r) {
#pragma unroll
    for (int s = 1; s < 16; s <<= 1) {
      float mo = __shfl_xor(m[r], s);
      float zo = __shfl_xor(z[r], s);
      float mn = fmaxf(m[r], mo);
      z[r] = z[r] * __expf(m[r] - mn) + zo * __expf(mo - mn);
      m[r] = mn;
    }
  }
  if (lr == 0) {
#pragma unroll
    for (int r = 0; r < 4; ++r) {
      int j = j0 + lg * 4 + r;
      mbuf[(size_t)b * S + j] = m[r];
      rzbuf[(size_t)b * S + j] = 1.0f / z[r];
    }
  }
}

// ---- 6. out = P @ V with P_ij = exp(a_ij - m_j) / Z_j -------------------
__global__ __launch_bounds__(256) void k_out(
    const u16* __restrict__ xb, const u16* __restrict__ Qb, const u16* __restrict__ VTb,
    const float* __restrict__ mbuf, const float* __restrict__ rzbuf,
    float* __restrict__ out) {
  __shared__ u16 Plds[4][16][72];  // per-wave 16x64 P tile, padded
  int it = blockIdx.x, b = blockIdx.y;
  int w = threadIdx.x >> 6, l = threadIdx.x & 63;
  int lr = l & 15, lg = l >> 4;
  int i0 = it * 64 + w * 16;
  const u16* xbase = xb + (size_t)b * S * D;
  const u16* qbase = Qb + (size_t)b * S * D;
  const u16* vbase = VTb + (size_t)b * D * S;
  const float* mb = mbuf + (size_t)b * S;
  const float* rzb = rzbuf + (size_t)b * S;
  bf16x8 qa0 = *(const bf16x8*)(qbase + (size_t)(i0 + lr) * D + lg * 8);
  bf16x8 qa1 = *(const bf16x8*)(qbase + (size_t)(i0 + lr) * D + 32 + lg * 8);
  f32x4 acc[4] = {};
  int njt = it + 1;
  for (int jt = 0; jt < njt; ++jt) {
    // scores phase: 4 sub-tiles of 16 j, C[row=i-local][col=j-local]
#pragma unroll
    for (int js = 0; js < 4; ++js) {
      int j16 = jt * 64 + js * 16;
      bf16x8 xb0 = *(const bf16x8*)(xbase + (size_t)(j16 + lr) * D + lg * 8);
      bf16x8 xb1 = *(const bf16x8*)(xbase + (size_t)(j16 + lr) * D + 32 + lg * 8);
      f32x4 c = {};
      c = __builtin_amdgcn_mfma_f32_16x16x32_bf16(qa0, xb0, c, 0, 0, 0);
      c = __builtin_amdgcn_mfma_f32_16x16x32_bf16(qa1, xb1, c, 0, 0, 0);
      int j = j16 + lr;
      float mj = mb[j];
      float rzj = rzb[j];
#pragma unroll
      for (int r = 0; r < 4; ++r) {
        int i = i0 + lg * 4 + r;
        float sc = c[r];
        float a = (j <= i && sc > 1.0f) ? sc * SCL : -1e30f;
        float wgt = __expf(a - mj) * rzj;
        Plds[w][lg * 4 + r][js * 16 + lr] = f2bf(wgt);
      }
    }
    asm volatile("s_waitcnt lgkmcnt(0)" ::: "memory");
    // PV phase: A = P (from LDS), B = V via VT (contiguous 16B frags)
#pragma unroll
    for (int kk = 0; kk < 2; ++kk) {
      bf16x8 pa = *(const bf16x8*)(&Plds[w][lr][kk * 32 + lg * 8]);
#pragma unroll
      for (int dt = 0; dt < 4; ++dt) {
        bf16x8 vbf = *(const bf16x8*)(vbase + (size_t)(dt * 16 + lr) * S + jt * 64 + kk * 32 + lg * 8);
        acc[dt] = __builtin_amdgcn_mfma_f32_16x16x32_bf16(pa, vbf, acc[dt], 0, 0, 0);
      }
    }
    asm volatile("s_waitcnt lgkmcnt(0)" ::: "memory");
  }
  float* obase = out + (size_t)b * S * D;
#pragma unroll
  for (int dt = 0; dt < 4; ++dt)
#pragma unroll
    for (int r = 0; r < 4; ++r) {
      int i = i0 + lg * 4 + r;
      obase[(size_t)i * D + dt * 16 + lr] = acc[dt][r];
    }
}

extern "C" void kernel_launch(void* const* d_in, const int* in_sizes, int n_in,
                              void* d_out, int out_size, void* d_ws, size_t ws_size,
                              hipStream_t stream) {
  const float* x  = (const float*)d_in[0];
  const float* wq = (const float*)d_in[1];
  const float* wv = (const float*)d_in[2];
  float* out = (float*)d_out;
  char* ws = (char*)d_ws;
  size_t off = 0;
  auto alloc = [&](size_t bytes) -> void* {
    void* p = ws + off; off += (bytes + 255) & ~255ULL; return p;
  };
  u16* wqb  = (u16*)alloc((size_t)S * S * 2);
  u16* wvb  = (u16*)alloc((size_t)S * S * 2);
  u16* xb   = (u16*)alloc((size_t)BATCH * S * D * 2);
  u16* xTb  = (u16*)alloc((size_t)BATCH * S * D * 2);
  u16* GTb  = (u16*)alloc((size_t)BATCH * S * D * 2);
  u16* Qb   = (u16*)alloc((size_t)BATCH * S * D * 2);
  u16* VTb  = (u16*)alloc((size_t)BATCH * S * D * 2);
  float* csum  = (float*)alloc((size_t)BATCH * 32 * 64 * 4);
  float* mbuf  = (float*)alloc((size_t)BATCH * S * 4);
  float* rzbuf = (float*)alloc((size_t)BATCH * S * 4);

  k_cvtw<<<4096, 256, 0, stream>>>(wq, wv, wqb, wvb);
  k_scan_a<<<dim3(32, BATCH), 64, 0, stream>>>(x, xb, xTb, csum);
  k_scan_b<<<dim3(32, BATCH), 64, 0, stream>>>(x, csum, GTb);
  k_gemm1<<<dim3(32, 2, BATCH), 256, 0, stream>>>(wqb, wvb, GTb, xTb, Qb, VTb);
  k_stats<<<dim3(32, BATCH), 256, 0, stream>>>(xb, Qb, mbuf, rzbuf);
  k_out<<<dim3(32, BATCH), 256, 0, stream>>>(xb, Qb, VTb, mbuf, rzbuf, out);
}

// Round 2
// 132.460 us; speedup vs baseline: 1.5189x; 1.5189x over previous
//
#include <hip/hip_runtime.h>

typedef unsigned short u16;
typedef __bf16 bf16;
typedef bf16 bf16x8 __attribute__((ext_vector_type(8)));
typedef float f32x4 __attribute__((ext_vector_type(4)));

#define S 2048
#define D 64
#define BATCH 4
#define SCL 0.022097086912079612f  /* 1/sqrt(2048) */

__device__ __forceinline__ u16 f2bf(float f) {
  union { float f; unsigned u; } v; v.f = f;
  return (u16)((v.u + 0x7FFFu + ((v.u >> 16) & 1u)) >> 16);
}

// ---- 1. chunk sums (16 rows/chunk) + x -> bf16 (row-major and transposed)
__global__ void k_scan_a(const float* __restrict__ x, u16* __restrict__ xb,
                         u16* __restrict__ xTb, float* __restrict__ csum) {
  int chunk = blockIdx.x, b = blockIdx.y, d = threadIdx.x;
  const float* xp = x + ((size_t)b * S + (size_t)chunk * 16) * D + d;
  float sum = 0.f;
#pragma unroll
  for (int s = 0; s < 16; ++s) {
    float v = xp[(size_t)s * D];
    sum += v;
    int sg = chunk * 16 + s;
    u16 h = f2bf(v);
    xb[((size_t)b * S + sg) * D + d] = h;
    xTb[((size_t)b * D + d) * S + sg] = h;
  }
  csum[((size_t)b * 128 + chunk) * 64 + d] = sum;
}

// ---- 2. finish scan -> GT (running mean, transposed, bf16) --------------
__global__ void k_scan_b(const float* __restrict__ x, const float* __restrict__ csum,
                         u16* __restrict__ GTb) {
  int chunk = blockIdx.x, b = blockIdx.y, d = threadIdx.x;
  float run = 0.f;
  for (int c = 0; c < chunk; ++c) run += csum[((size_t)b * 128 + c) * 64 + d];
  const float* xp = x + ((size_t)b * S + (size_t)chunk * 16) * D + d;
#pragma unroll
  for (int s = 0; s < 16; ++s) {
    run += xp[(size_t)s * D];
    int sg = chunk * 16 + s;
    GTb[((size_t)b * D + d) * S + sg] = f2bf(run / (float)(sg + 1));
  }
}

// ---- 3. GEMM1: Q = W_Q @ G, V = W_V @ x  (fp32 W converted in-register) --
// mat==0 -> Q (row-major out), mat==1 -> V (transposed out VT[d][s])
__global__ __launch_bounds__(256) void k_gemm1(
    const float* __restrict__ wq, const float* __restrict__ wv,
    const u16* __restrict__ GTb, const u16* __restrict__ xTb,
    u16* __restrict__ Qb, u16* __restrict__ VTb) {
  int mt = blockIdx.x, mat = blockIdx.y, b = blockIdx.z;
  int w = threadIdx.x >> 6, l = threadIdx.x & 63;
  int lr = l & 15, lg = l >> 4;
  int row = mt * 64 + w * 16 + lr;
  const float* W = mat ? wv : wq;
  const u16* Bsrc = (mat ? xTb : GTb) + (size_t)b * D * S;
  f32x4 acc[4] = {};
  const float* wrow = W + (size_t)row * S + lg * 8;
  const u16* brow0 = Bsrc + (size_t)(0 * 16 + lr) * S + lg * 8;
  const u16* brow1 = Bsrc + (size_t)(1 * 16 + lr) * S + lg * 8;
  const u16* brow2 = Bsrc + (size_t)(2 * 16 + lr) * S + lg * 8;
  const u16* brow3 = Bsrc + (size_t)(3 * 16 + lr) * S + lg * 8;
  for (int k0 = 0; k0 < S; k0 += 32) {
    float4 f0 = *(const float4*)(wrow + k0);
    float4 f1 = *(const float4*)(wrow + k0 + 4);
    union { u16 s[8]; bf16x8 v; } ua;
    ua.s[0]=f2bf(f0.x); ua.s[1]=f2bf(f0.y); ua.s[2]=f2bf(f0.z); ua.s[3]=f2bf(f0.w);
    ua.s[4]=f2bf(f1.x); ua.s[5]=f2bf(f1.y); ua.s[6]=f2bf(f1.z); ua.s[7]=f2bf(f1.w);
    bf16x8 a = ua.v;
    bf16x8 b0 = *(const bf16x8*)(brow0 + k0);
    bf16x8 b1 = *(const bf16x8*)(brow1 + k0);
    bf16x8 b2 = *(const bf16x8*)(brow2 + k0);
    bf16x8 b3 = *(const bf16x8*)(brow3 + k0);
    acc[0] = __builtin_amdgcn_mfma_f32_16x16x32_bf16(a, b0, acc[0], 0, 0, 0);
    acc[1] = __builtin_amdgcn_mfma_f32_16x16x32_bf16(a, b1, acc[1], 0, 0, 0);
    acc[2] = __builtin_amdgcn_mfma_f32_16x16x32_bf16(a, b2, acc[2], 0, 0, 0);
    acc[3] = __builtin_amdgcn_mfma_f32_16x16x32_bf16(a, b3, acc[3], 0, 0, 0);
  }
#pragma unroll
  for (int dt = 0; dt < 4; ++dt)
#pragma unroll
    for (int r = 0; r < 4; ++r) {
      int m = mt * 64 + w * 16 + lg * 4 + r;
      int n = dt * 16 + lr;
      u16 hv = f2bf(acc[dt][r]);
      if (mat) VTb[((size_t)b * D + n) * S + m] = hv;
      else     Qb[((size_t)b * S + m) * D + n] = hv;
    }
}

// ---- 4. column stats: m_j, Z_j over i>=j. One block per 16 j's; 4 waves
//      split the i-range 4-way, combine via shfl + LDS. ------------------
__global__ __launch_bounds__(256) void k_stats(
    const u16* __restrict__ xb, const u16* __restrict__ Qb,
    float* __restrict__ mbuf, float* __restrict__ rzbuf) {
  __shared__ float ms[4][16], zs[4][16];
  int jg = blockIdx.x, b = blockIdx.y;
  int tid = threadIdx.x;
  int w = tid >> 6, l = tid & 63;
  int lr = l & 15, lg = l >> 4;
  int j0 = jg * 16;
  const u16* xbase = xb + (size_t)b * S * D;
  const u16* qbase = Qb + (size_t)b * S * D;
  bf16x8 xa0 = *(const bf16x8*)(xbase + (size_t)(j0 + lr) * D + lg * 8);
  bf16x8 xa1 = *(const bf16x8*)(xbase + (size_t)(j0 + lr) * D + 32 + lg * 8);
  float m[4] = {-1e30f, -1e30f, -1e30f, -1e30f};
  float z[4] = {0.f, 0.f, 0.f, 0.f};
  for (int i16 = j0 + w * 16; i16 < S; i16 += 64) {
    bf16x8 q0 = *(const bf16x8*)(qbase + (size_t)(i16 + lr) * D + lg * 8);
    bf16x8 q1 = *(const bf16x8*)(qbase + (size_t)(i16 + lr) * D + 32 + lg * 8);
    f32x4 c = {};
    c = __builtin_amdgcn_mfma_f32_16x16x32_bf16(xa0, q0, c, 0, 0, 0);
    c = __builtin_amdgcn_mfma_f32_16x16x32_bf16(xa1, q1, c, 0, 0, 0);
    int i = i16 + lr;
#pragma unroll
    for (int r = 0; r < 4; ++r) {
      int j = j0 + lg * 4 + r;
      float sc = c[r];
      float a = (i >= j && sc > 1.0f) ? sc * SCL : -1e30f;
      float mn = fmaxf(m[r], a);
      z[r] = z[r] * __expf(m[r] - mn) + __expf(a - mn);
      m[r] = mn;
    }
  }
#pragma unroll
  for (int r = 0; r < 4; ++r) {
#pragma unroll
    for (int s = 1; s < 16; s <<= 1) {
      float mo = __shfl_xor(m[r], s);
      float zo = __shfl_xor(z[r], s);
      float mn = fmaxf(m[r], mo);
      z[r] = z[r] * __expf(m[r] - mn) + zo * __expf(mo - mn);
      m[r] = mn;
    }
  }
  if (lr == 0) {
#pragma unroll
    for (int r = 0; r < 4; ++r) {
      ms[w][lg * 4 + r] = m[r];
      zs[w][lg * 4 + r] = z[r];
    }
  }
  __syncthreads();
  if (tid < 16) {
    float mf = -1e30f;
#pragma unroll
    for (int ww = 0; ww < 4; ++ww) mf = fmaxf(mf, ms[ww][tid]);
    float zf = 0.f;
#pragma unroll
    for (int ww = 0; ww < 4; ++ww) zf += zs[ww][tid] * __expf(ms[ww][tid] - mf);
    mbuf[(size_t)b * S + j0 + tid] = mf;
    rzbuf[(size_t)b * S + j0 + tid] = 1.0f / zf;
  }
}

// ---- 5. out += P_chunk @ V_chunk. One block per (i-tile, 4-j-tile chunk).
__global__ __launch_bounds__(256) void k_out(
    const u16* __restrict__ xb, const u16* __restrict__ Qb, const u16* __restrict__ VTb,
    const float* __restrict__ mbuf, const float* __restrict__ rzbuf,
    float* __restrict__ out) {
  __shared__ u16 Plds[4][16][72];  // per-wave 16x64 P tile, padded
  // decode blockIdx.x -> (it, jc): nchunk(it) = ceil((it+1)/4)
  int bx = blockIdx.x, b = blockIdx.y;
  int it = 0, jc = 0, base = 0;
  for (int t = 0; t < 32; ++t) {
    int nc = (t + 4) >> 2;
    if (bx < base + nc) { it = t; jc = bx - base; break; }
    base += nc;
  }
  int w = threadIdx.x >> 6, l = threadIdx.x & 63;
  int lr = l & 15, lg = l >> 4;
  int i0 = it * 64 + w * 16;
  const u16* xbase = xb + (size_t)b * S * D;
  const u16* qbase = Qb + (size_t)b * S * D;
  const u16* vbase = VTb + (size_t)b * D * S;
  const float* mb = mbuf + (size_t)b * S;
  const float* rzb = rzbuf + (size_t)b * S;
  bf16x8 qa0 = *(const bf16x8*)(qbase + (size_t)(i0 + lr) * D + lg * 8);
  bf16x8 qa1 = *(const bf16x8*)(qbase + (size_t)(i0 + lr) * D + 32 + lg * 8);
  f32x4 acc[4] = {};
  int jt_end = min(jc * 4 + 4, it + 1);
  for (int jt = jc * 4; jt < jt_end; ++jt) {
    // scores phase: 4 sub-tiles of 16 j, C[row=i-local][col=j-local]
#pragma unroll
    for (int js = 0; js < 4; ++js) {
      int j16 = jt * 64 + js * 16;
      bf16x8 xb0 = *(const bf16x8*)(xbase + (size_t)(j16 + lr) * D + lg * 8);
      bf16x8 xb1 = *(const bf16x8*)(xbase + (size_t)(j16 + lr) * D + 32 + lg * 8);
      f32x4 c = {};
      c = __builtin_amdgcn_mfma_f32_16x16x32_bf16(qa0, xb0, c, 0, 0, 0);
      c = __builtin_amdgcn_mfma_f32_16x16x32_bf16(qa1, xb1, c, 0, 0, 0);
      int j = j16 + lr;
      float mj = mb[j];
      float rzj = rzb[j];
#pragma unroll
      for (int r = 0; r < 4; ++r) {
        int i = i0 + lg * 4 + r;
        float sc = c[r];
        float a = (j <= i && sc > 1.0f) ? sc * SCL : -1e30f;
        float wgt = __expf(a - mj) * rzj;
        Plds[w][lg * 4 + r][js * 16 + lr] = f2bf(wgt);
      }
    }
    asm volatile("s_waitcnt lgkmcnt(0)" ::: "memory");
    // PV phase: A = P (from LDS), B = V via VT (contiguous 16B frags)
#pragma unroll
    for (int kk = 0; kk < 2; ++kk) {
      bf16x8 pa = *(const bf16x8*)(&Plds[w][lr][kk * 32 + lg * 8]);
#pragma unroll
      for (int dt = 0; dt < 4; ++dt) {
        bf16x8 vbf = *(const bf16x8*)(vbase + (size_t)(dt * 16 + lr) * S + jt * 64 + kk * 32 + lg * 8);
        acc[dt] = __builtin_amdgcn_mfma_f32_16x16x32_bf16(pa, vbf, acc[dt], 0, 0, 0);
      }
    }
    asm volatile("s_waitcnt lgkmcnt(0)" ::: "memory");
  }
  float* obase = out + (size_t)b * S * D;
#pragma unroll
  for (int dt = 0; dt < 4; ++dt)
#pragma unroll
    for (int r = 0; r < 4; ++r) {
      int i = i0 + lg * 4 + r;
      atomicAdd(&obase[(size_t)i * D + dt * 16 + lr], acc[dt][r]);
    }
}

extern "C" void kernel_launch(void* const* d_in, const int* in_sizes, int n_in,
                              void* d_out, int out_size, void* d_ws, size_t ws_size,
                              hipStream_t stream) {
  const float* x  = (const float*)d_in[0];
  const float* wq = (const float*)d_in[1];
  const float* wv = (const float*)d_in[2];
  float* out = (float*)d_out;
  char* ws = (char*)d_ws;
  size_t off = 0;
  auto alloc = [&](size_t bytes) -> void* {
    void* p = ws + off; off += (bytes + 255) & ~255ULL; return p;
  };
  u16* xb   = (u16*)alloc((size_t)BATCH * S * D * 2);
  u16* xTb  = (u16*)alloc((size_t)BATCH * S * D * 2);
  u16* GTb  = (u16*)alloc((size_t)BATCH * S * D * 2);
  u16* Qb   = (u16*)alloc((size_t)BATCH * S * D * 2);
  u16* VTb  = (u16*)alloc((size_t)BATCH * S * D * 2);
  float* csum  = (float*)alloc((size_t)BATCH * 128 * 64 * 4);
  float* mbuf  = (float*)alloc((size_t)BATCH * S * 4);
  float* rzbuf = (float*)alloc((size_t)BATCH * S * 4);

  hipMemsetAsync(out, 0, (size_t)out_size * 4, stream);
  k_scan_a<<<dim3(128, BATCH), 64, 0, stream>>>(x, xb, xTb, csum);
  k_scan_b<<<dim3(128, BATCH), 64, 0, stream>>>(x, csum, GTb);
  k_gemm1<<<dim3(32, 2, BATCH), 256, 0, stream>>>(wq, wv, GTb, xTb, Qb, VTb);
  k_stats<<<dim3(128, BATCH), 256, 0, stream>>>(xb, Qb, mbuf, rzbuf);
  k_out<<<dim3(144, BATCH), 256, 0, stream>>>(xb, Qb, VTb, mbuf, rzbuf, out);
}

// Round 3
// 132.143 us; speedup vs baseline: 1.5225x; 1.0024x over previous
//
#include <hip/hip_runtime.h>

typedef unsigned short u16;
typedef __bf16 bf16;
typedef bf16 bf16x8 __attribute__((ext_vector_type(8)));
typedef float f32x4 __attribute__((ext_vector_type(4)));

#define S 2048
#define D 64
#define BATCH 4
#define SCL 0.022097086912079612f  /* 1/sqrt(2048) */

__device__ __forceinline__ u16 f2bf(float f) {
  union { float f; unsigned u; } v; v.f = f;
  return (u16)((v.u + 0x7FFFu + ((v.u >> 16) & 1u)) >> 16);
}

// ---- 1. chunk sums (16 rows/chunk) + x -> bf16 (row-major and transposed)
__global__ void k_scan_a(const float* __restrict__ x, u16* __restrict__ xb,
                         u16* __restrict__ xTb, float* __restrict__ csum) {
  int chunk = blockIdx.x, b = blockIdx.y, d = threadIdx.x;
  const float* xp = x + ((size_t)b * S + (size_t)chunk * 16) * D + d;
  float sum = 0.f;
#pragma unroll
  for (int s = 0; s < 16; ++s) {
    float v = xp[(size_t)s * D];
    sum += v;
    int sg = chunk * 16 + s;
    u16 h = f2bf(v);
    xb[((size_t)b * S + sg) * D + d] = h;
    xTb[((size_t)b * D + d) * S + sg] = h;
  }
  csum[((size_t)b * 128 + chunk) * 64 + d] = sum;
}

// ---- 2. finish scan -> GT (running mean, transposed, bf16) --------------
__global__ void k_scan_b(const float* __restrict__ x, const float* __restrict__ csum,
                         u16* __restrict__ GTb) {
  int chunk = blockIdx.x, b = blockIdx.y, d = threadIdx.x;
  float run = 0.f;
  for (int c = 0; c < chunk; ++c) run += csum[((size_t)b * 128 + c) * 64 + d];
  const float* xp = x + ((size_t)b * S + (size_t)chunk * 16) * D + d;
#pragma unroll
  for (int s = 0; s < 16; ++s) {
    run += xp[(size_t)s * D];
    int sg = chunk * 16 + s;
    GTb[((size_t)b * D + d) * S + sg] = f2bf(run / (float)(sg + 1));
  }
}

// ---- 3. GEMM1: Q = W_Q @ G, V = W_V @ x. Split-K: block = (16 rows, mat, b),
//      4 waves each take K-chunk of 512, LDS fp32 reduce, bf16 store. -----
__global__ __launch_bounds__(256) void k_gemm1(
    const float* __restrict__ wq, const float* __restrict__ wv,
    const u16* __restrict__ GTb, const u16* __restrict__ xTb,
    u16* __restrict__ Qb, u16* __restrict__ VTb) {
  __shared__ float red[4][4][4][64];  // [wave][dt][r][lane], 16 KB
  int bx = blockIdx.x;
  int mt = bx >> 2, b = bx & 3;       // batch-siblings adjacent -> share W in L2
  int mat = blockIdx.y;
  int w = threadIdx.x >> 6, l = threadIdx.x & 63;
  int lr = l & 15, lg = l >> 4;
  int row = mt * 16 + lr;
  const float* W = mat ? wv : wq;
  const u16* Bsrc = (mat ? xTb : GTb) + (size_t)b * D * S;
  f32x4 acc[4] = {};
  const float* wrow = W + (size_t)row * S + w * 512 + lg * 8;
  const u16* br0 = Bsrc + (size_t)(0 * 16 + lr) * S + w * 512 + lg * 8;
  const u16* br1 = Bsrc + (size_t)(1 * 16 + lr) * S + w * 512 + lg * 8;
  const u16* br2 = Bsrc + (size_t)(2 * 16 + lr) * S + w * 512 + lg * 8;
  const u16* br3 = Bsrc + (size_t)(3 * 16 + lr) * S + w * 512 + lg * 8;
#pragma unroll 4
  for (int k0 = 0; k0 < 512; k0 += 32) {
    float4 f0 = *(const float4*)(wrow + k0);
    float4 f1 = *(const float4*)(wrow + k0 + 4);
    union { u16 s[8]; bf16x8 v; } ua;
    ua.s[0]=f2bf(f0.x); ua.s[1]=f2bf(f0.y); ua.s[2]=f2bf(f0.z); ua.s[3]=f2bf(f0.w);
    ua.s[4]=f2bf(f1.x); ua.s[5]=f2bf(f1.y); ua.s[6]=f2bf(f1.z); ua.s[7]=f2bf(f1.w);
    bf16x8 a = ua.v;
    bf16x8 b0 = *(const bf16x8*)(br0 + k0);
    bf16x8 b1 = *(const bf16x8*)(br1 + k0);
    bf16x8 b2 = *(const bf16x8*)(br2 + k0);
    bf16x8 b3 = *(const bf16x8*)(br3 + k0);
    acc[0] = __builtin_amdgcn_mfma_f32_16x16x32_bf16(a, b0, acc[0], 0, 0, 0);
    acc[1] = __builtin_amdgcn_mfma_f32_16x16x32_bf16(a, b1, acc[1], 0, 0, 0);
    acc[2] = __builtin_amdgcn_mfma_f32_16x16x32_bf16(a, b2, acc[2], 0, 0, 0);
    acc[3] = __builtin_amdgcn_mfma_f32_16x16x32_bf16(a, b3, acc[3], 0, 0, 0);
  }
#pragma unroll
  for (int dt = 0; dt < 4; ++dt)
#pragma unroll
    for (int r = 0; r < 4; ++r) red[w][dt][r][l] = acc[dt][r];
  __syncthreads();
  // wave w owns output dt = w
#pragma unroll
  for (int r = 0; r < 4; ++r) {
    float s = red[0][w][r][l] + red[1][w][r][l] + red[2][w][r][l] + red[3][w][r][l];
    int m = mt * 16 + lg * 4 + r;
    int n = w * 16 + lr;
    u16 hv = f2bf(s);
    if (mat) VTb[((size_t)b * D + n) * S + m] = hv;
    else     Qb[((size_t)b * S + m) * D + n] = hv;
  }
}

// ---- 4. column stats: m_j, Z_j over i>=j. One block per 16 j's; 4 waves
//      split the i-range 4-way, combine via shfl + LDS. ------------------
__global__ __launch_bounds__(256) void k_stats(
    const u16* __restrict__ xb, const u16* __restrict__ Qb,
    float* __restrict__ mbuf, float* __restrict__ rzbuf) {
  __shared__ float ms[4][16], zs[4][16];
  int jg = blockIdx.x, b = blockIdx.y;
  int tid = threadIdx.x;
  int w = tid >> 6, l = tid & 63;
  int lr = l & 15, lg = l >> 4;
  int j0 = jg * 16;
  const u16* xbase = xb + (size_t)b * S * D;
  const u16* qbase = Qb + (size_t)b * S * D;
  bf16x8 xa0 = *(const bf16x8*)(xbase + (size_t)(j0 + lr) * D + lg * 8);
  bf16x8 xa1 = *(const bf16x8*)(xbase + (size_t)(j0 + lr) * D + 32 + lg * 8);
  float m[4] = {-1e30f, -1e30f, -1e30f, -1e30f};
  float z[4] = {0.f, 0.f, 0.f, 0.f};
  for (int i16 = j0 + w * 16; i16 < S; i16 += 64) {
    bf16x8 q0 = *(const bf16x8*)(qbase + (size_t)(i16 + lr) * D + lg * 8);
    bf16x8 q1 = *(const bf16x8*)(qbase + (size_t)(i16 + lr) * D + 32 + lg * 8);
    f32x4 c = {};
    c = __builtin_amdgcn_mfma_f32_16x16x32_bf16(xa0, q0, c, 0, 0, 0);
    c = __builtin_amdgcn_mfma_f32_16x16x32_bf16(xa1, q1, c, 0, 0, 0);
    int i = i16 + lr;
#pragma unroll
    for (int r = 0; r < 4; ++r) {
      int j = j0 + lg * 4 + r;
      float sc = c[r];
      float a = (i >= j && sc > 1.0f) ? sc * SCL : -1e30f;
      float mn = fmaxf(m[r], a);
      z[r] = z[r] * __expf(m[r] - mn) + __expf(a - mn);
      m[r] = mn;
    }
  }
#pragma unroll
  for (int r = 0; r < 4; ++r) {
#pragma unroll
    for (int s = 1; s < 16; s <<= 1) {
      float mo = __shfl_xor(m[r], s);
      float zo = __shfl_xor(z[r], s);
      float mn = fmaxf(m[r], mo);
      z[r] = z[r] * __expf(m[r] - mn) + zo * __expf(mo - mn);
      m[r] = mn;
    }
  }
  if (lr == 0) {
#pragma unroll
    for (int r = 0; r < 4; ++r) {
      ms[w][lg * 4 + r] = m[r];
      zs[w][lg * 4 + r] = z[r];
    }
  }
  __syncthreads();
  if (tid < 16) {
    float mf = -1e30f;
#pragma unroll
    for (int ww = 0; ww < 4; ++ww) mf = fmaxf(mf, ms[ww][tid]);
    float zf = 0.f;
#pragma unroll
    for (int ww = 0; ww < 4; ++ww) zf += zs[ww][tid] * __expf(ms[ww][tid] - mf);
    mbuf[(size_t)b * S + j0 + tid] = mf;
    rzbuf[(size_t)b * S + j0 + tid] = 1.0f / zf;
  }
}

// ---- 5. out += P_chunk @ V_chunk. One block per (i-tile, 4-j-tile chunk).
__global__ __launch_bounds__(256) void k_out(
    const u16* __restrict__ xb, const u16* __restrict__ Qb, const u16* __restrict__ VTb,
    const float* __restrict__ mbuf, const float* __restrict__ rzbuf,
    float* __restrict__ out) {
  __shared__ u16 Plds[4][16][72];  // per-wave 16x64 P tile, padded
  // decode blockIdx.x -> (it, jc): nchunk(it) = ceil((it+1)/4)
  int bx = blockIdx.x, b = blockIdx.y;
  int it = 0, jc = 0, base = 0;
  for (int t = 0; t < 32; ++t) {
    int nc = (t + 4) >> 2;
    if (bx < base + nc) { it = t; jc = bx - base; break; }
    base += nc;
  }
  int w = threadIdx.x >> 6, l = threadIdx.x & 63;
  int lr = l & 15, lg = l >> 4;
  int i0 = it * 64 + w * 16;
  const u16* xbase = xb + (size_t)b * S * D;
  const u16* qbase = Qb + (size_t)b * S * D;
  const u16* vbase = VTb + (size_t)b * D * S;
  const float* mb = mbuf + (size_t)b * S;
  const float* rzb = rzbuf + (size_t)b * S;
  bf16x8 qa0 = *(const bf16x8*)(qbase + (size_t)(i0 + lr) * D + lg * 8);
  bf16x8 qa1 = *(const bf16x8*)(qbase + (size_t)(i0 + lr) * D + 32 + lg * 8);
  f32x4 acc[4] = {};
  int jt_end = min(jc * 4 + 4, it + 1);
  for (int jt = jc * 4; jt < jt_end; ++jt) {
    // scores phase: 4 sub-tiles of 16 j, C[row=i-local][col=j-local]
#pragma unroll
    for (int js = 0; js < 4; ++js) {
      int j16 = jt * 64 + js * 16;
      bf16x8 xb0 = *(const bf16x8*)(xbase + (size_t)(j16 + lr) * D + lg * 8);
      bf16x8 xb1 = *(const bf16x8*)(xbase + (size_t)(j16 + lr) * D + 32 + lg * 8);
      f32x4 c = {};
      c = __builtin_amdgcn_mfma_f32_16x16x32_bf16(qa0, xb0, c, 0, 0, 0);
      c = __builtin_amdgcn_mfma_f32_16x16x32_bf16(qa1, xb1, c, 0, 0, 0);
      int j = j16 + lr;
      float mj = mb[j];
      float rzj = rzb[j];
#pragma unroll
      for (int r = 0; r < 4; ++r) {
        int i = i0 + lg * 4 + r;
        float sc = c[r];
        float a = (j <= i && sc > 1.0f) ? sc * SCL : -1e30f;
        float wgt = __expf(a - mj) * rzj;
        Plds[w][lg * 4 + r][js * 16 + lr] = f2bf(wgt);
      }
    }
    asm volatile("s_waitcnt lgkmcnt(0)" ::: "memory");
    // PV phase: A = P (from LDS), B = V via VT (contiguous 16B frags)
#pragma unroll
    for (int kk = 0; kk < 2; ++kk) {
      bf16x8 pa = *(const bf16x8*)(&Plds[w][lr][kk * 32 + lg * 8]);
#pragma unroll
      for (int dt = 0; dt < 4; ++dt) {
        bf16x8 vbf = *(const bf16x8*)(vbase + (size_t)(dt * 16 + lr) * S + jt * 64 + kk * 32 + lg * 8);
        acc[dt] = __builtin_amdgcn_mfma_f32_16x16x32_bf16(pa, vbf, acc[dt], 0, 0, 0);
      }
    }
    asm volatile("s_waitcnt lgkmcnt(0)" ::: "memory");
  }
  float* obase = out + (size_t)b * S * D;
#pragma unroll
  for (int dt = 0; dt < 4; ++dt)
#pragma unroll
    for (int r = 0; r < 4; ++r) {
      int i = i0 + lg * 4 + r;
      atomicAdd(&obase[(size_t)i * D + dt * 16 + lr], acc[dt][r]);
    }
}

extern "C" void kernel_launch(void* const* d_in, const int* in_sizes, int n_in,
                              void* d_out, int out_size, void* d_ws, size_t ws_size,
                              hipStream_t stream) {
  const float* x  = (const float*)d_in[0];
  const float* wq = (const float*)d_in[1];
  const float* wv = (const float*)d_in[2];
  float* out = (float*)d_out;
  char* ws = (char*)d_ws;
  size_t off = 0;
  auto alloc = [&](size_t bytes) -> void* {
    void* p = ws + off; off += (bytes + 255) & ~255ULL; return p;
  };
  u16* xb   = (u16*)alloc((size_t)BATCH * S * D * 2);
  u16* xTb  = (u16*)alloc((size_t)BATCH * S * D * 2);
  u16* GTb  = (u16*)alloc((size_t)BATCH * S * D * 2);
  u16* Qb   = (u16*)alloc((size_t)BATCH * S * D * 2);
  u16* VTb  = (u16*)alloc((size_t)BATCH * S * D * 2);
  float* csum  = (float*)alloc((size_t)BATCH * 128 * 64 * 4);
  float* mbuf  = (float*)alloc((size_t)BATCH * S * 4);
  float* rzbuf = (float*)alloc((size_t)BATCH * S * 4);

  hipMemsetAsync(out, 0, (size_t)out_size * 4, stream);
  k_scan_a<<<dim3(128, BATCH), 64, 0, stream>>>(x, xb, xTb, csum);
  k_scan_b<<<dim3(128, BATCH), 64, 0, stream>>>(x, csum, GTb);
  k_gemm1<<<dim3(512, 2), 256, 0, stream>>>(wq, wv, GTb, xTb, Qb, VTb);
  k_stats<<<dim3(128, BATCH), 256, 0, stream>>>(xb, Qb, mbuf, rzbuf);
  k_out<<<dim3(144, BATCH), 256, 0, stream>>>(xb, Qb, VTb, mbuf, rzbuf, out);
}